// Round 1
// baseline (237.579 us; speedup 1.0000x reference)
//
#include <hip/hip_runtime.h>

#define B_DIM 8
#define N_DIM 2048
#define C_DIM 256
#define K_SEL 1024

typedef __attribute__((ext_vector_type(8))) short short8;
typedef __attribute__((ext_vector_type(4))) float f32x4;

__device__ __forceinline__ unsigned int bf16rne(float x) {
  unsigned int u = __float_as_uint(x);
  return (u + 0x7fffu + ((u >> 16) & 1u)) >> 16;
}

// ---------------- LayerNorm, numpy-bit-exact, LDS-staged (unchanged, verified) ----------------
__global__ __launch_bounds__(64) void ln_lds(const float* __restrict__ feat,
    const float* __restrict__ gamma, const float* __restrict__ beta,
    float* __restrict__ fbuf) {
  __shared__ float tile[256 * 64];   // 64 KB exactly
  const int t = threadIdx.x;
  const int m0 = blockIdx.x << 6;
  const int b = m0 >> 11, n0 = m0 & 2047;

  const int cg = t >> 4, nl4 = (t & 15) << 2;
  for (int pass = 0; pass < 64; ++pass) {
    const int c = (pass << 2) + cg;
    const float4 v = *(const float4*)(feat + (((long)((b << 8) + c)) << 11) + n0 + nl4);
    const int sw = c & 31;
    float* row = tile + (c << 6);
    row[(nl4 + 0) ^ sw] = v.x; row[(nl4 + 1) ^ sw] = v.y;
    row[(nl4 + 2) ^ sw] = v.z; row[(nl4 + 3) ^ sw] = v.w;
  }
  __syncthreads();

  // mean: sequential ascending single chain (numpy strided-axis outer reduction)
  float acc = tile[t];
  for (int c = 1; c < 256; ++c) acc = __fadd_rn(acc, tile[(c << 6) + (t ^ (c & 31))]);
  const float mu = __fdiv_rn(acc, 256.0f);

  // var: numpy pairwise (2 halves x 8 accumulators) on contiguous (x-mu)^2
  float pw[2];
#pragma unroll
  for (int blk = 0; blk < 2; ++blk) {
    const int c0 = blk << 7;
    float r8[8];
#pragma unroll
    for (int j = 0; j < 8; ++j) {
      float d = __fsub_rn(tile[((c0 + j) << 6) + (t ^ ((c0 + j) & 31))], mu);
      r8[j] = __fmul_rn(d, d);
    }
    for (int i = 8; i < 128; i += 8) {
#pragma unroll
      for (int j = 0; j < 8; ++j) {
        const int c = c0 + i + j;
        float d = __fsub_rn(tile[(c << 6) + (t ^ (c & 31))], mu);
        r8[j] = __fadd_rn(r8[j], __fmul_rn(d, d));
      }
    }
    pw[blk] = __fadd_rn(__fadd_rn(__fadd_rn(r8[0], r8[1]), __fadd_rn(r8[2], r8[3])),
                        __fadd_rn(__fadd_rn(r8[4], r8[5]), __fadd_rn(r8[6], r8[7])));
  }
  const float var = __fdiv_rn(__fadd_rn(pw[0], pw[1]), 256.0f);
  const float rs = __fdiv_rn(1.0f, __fsqrt_rn(__fadd_rn(var, 1e-6f)));

  float ga[4], be[4];
#pragma unroll
  for (int q = 0; q < 4; ++q) { ga[q] = gamma[(q << 6) + t]; be[q] = beta[(q << 6) + t]; }
  for (int r = 0; r < 64; ++r) {
    const float mu_r = __shfl(mu, r, 64);
    const float rs_r = __shfl(rs, r, 64);
    float* orow = fbuf + (((long)(m0 + r)) << 8);
#pragma unroll
    for (int q = 0; q < 4; ++q) {
      const int c = (q << 6) + t;
      const float x = tile[(c << 6) + (r ^ (c & 31))];
      orow[c] = __fadd_rn(__fmul_rn(__fmul_rn(__fsub_rn(x, mu_r), rs_r), ga[q]), be[q]);
    }
  }
}

// ---------------- fused down-GEMM + w-chain, 512 threads (bit-exact chains) ----------------
// v2: A operand is wave-uniform (rowT = t>>6) -> read it straight from global fbuf as
// 64-lane-broadcast dwordx4 loads (L1/L2 hit, one txn) instead of 2 broadcast ds_reads.
// LDS traffic per kk per wave drops 3 reads -> 1 (the spanning B read), moving the kernel
// from LDS-issue-bound (~37% VALUBusy) to VALU-bound. Wd1 chunk staging is now
// double-buffered (regs -> alternate LDS buffer) with ONE barrier per 16-k chunk.
// FMA chain per (m,c) stays ascending-k single chain -> bit-exact w (top-k ordering safe).
__global__ void __launch_bounds__(512) wgemm_w(
    const float* __restrict__ A, const float* __restrict__ Wd1,
    const float* __restrict__ bd1, const float* __restrict__ Wd2,
    const float* __restrict__ bd2, float* __restrict__ wkey) {
  __shared__ __align__(16) char smem[65536];
  float (*Bs0)[260] = (float (*)[260])smem;              // 16x260x4 = 16640 B
  float (*Bs1)[260] = (float (*)[260])(smem + 16640);    // 16640 B (double buffer)
  float* H = (float*)smem;                               // 256x64 f32 = 64 KB (epilogue alias)

  const int t = threadIdx.x;
  const int m0 = blockIdx.x << 6;
  const int rowT = t >> 6, colT = t & 63;                // rowT uniform per wave
  const int bk = t >> 5, bc = (t & 31) << 3;             // B loaders: all 512
  const float* arow0 = A + ((long)(m0 + (rowT << 3)) << 8);  // wave's 8 rows; row i at +i*256

  float acc[8][4] = {};

  // B prologue: stage chunk 0 into Bs0
  {
    const float* brow = Wd1 + ((bk << 8) + bc);
    *(float4*)&Bs0[bk][bc]     = *(const float4*)brow;
    *(float4*)&Bs0[bk][bc + 4] = *(const float4*)(brow + 4);
  }

  // A prefetch: k = 0..3 for the wave's 8 rows (broadcast loads)
  float4 a_cur[8], a_nxt[8];
#pragma unroll
  for (int i = 0; i < 8; ++i) a_cur[i] = *(const float4*)(arow0 + (i << 8));

  __syncthreads();

  int cur = 0;
  for (int c16 = 0; c16 < 16; ++c16) {
    // issue next B-chunk global loads (wraps to chunk 0 on last iter; unused then)
    float4 r0, r1;
    {
      const int knext = (c16 + 1) & 15;
      const float* brow = Wd1 + (((knext << 4) + bk) << 8) + bc;
      r0 = *(const float4*)brow;
      r1 = *(const float4*)(brow + 4);
    }
    float (*Bsc)[260] = cur ? Bs1 : Bs0;
#pragma unroll
    for (int ks = 0; ks < 16; ks += 4) {
      // prefetch next 4 k-values of A (wraps harmlessly at k=256)
      const int ka = ((c16 << 4) + ks + 4) & 255;
#pragma unroll
      for (int i = 0; i < 8; ++i) a_nxt[i] = *(const float4*)(arow0 + (i << 8) + ka);
#pragma unroll
      for (int kk = 0; kk < 4; ++kk) {   // k ascending: single FMA chain per (m,c)
        const float4 b = *(const float4*)&Bsc[ks + kk][colT << 2];
        const float bbv[4] = {b.x, b.y, b.z, b.w};
#pragma unroll
        for (int i = 0; i < 8; ++i) {
          const float av = (kk == 0) ? a_cur[i].x : (kk == 1) ? a_cur[i].y
                         : (kk == 2) ? a_cur[i].z : a_cur[i].w;
#pragma unroll
          for (int j = 0; j < 4; ++j)
            acc[i][j] = __fmaf_rn(av, bbv[j], acc[i][j]);
        }
      }
#pragma unroll
      for (int i = 0; i < 8; ++i) a_cur[i] = a_nxt[i];
    }
    if (c16 < 15) {
      // write next chunk into the other buffer; safe: everyone finished reading it
      // (it was the read buffer before the previous barrier)
      float (*Bsn)[260] = cur ? Bs0 : Bs1;
      *(float4*)&Bsn[bk][bc]     = r0;
      *(float4*)&Bsn[bk][bc + 4] = r1;
      cur ^= 1;
    }
    __syncthreads();   // one barrier per chunk; final one guards H alias below
  }

  // epilogue: bias + relu -> H[c][m] swizzled (unchanged, verified)
  const float4 bd = *(const float4*)(bd1 + (colT << 2));
  const float ba[4] = {bd.x, bd.y, bd.z, bd.w};
#pragma unroll
  for (int i = 0; i < 8; ++i) {
    const int m = (rowT << 3) + i;
#pragma unroll
    for (int j = 0; j < 4; ++j) {
      const int c = (colT << 2) + j;
      H[(c << 6) + (m ^ ((c >> 2) & 31))] = fmaxf(__fadd_rn(acc[i][j], ba[j]), 0.0f);
    }
  }
  __syncthreads();

  // w-chain: ascending-c single FMA chain; key = (w+bd2)/0.1f (unchanged, verified)
  if (t < 64) {
    float wa = 0.0f;
    for (int c = 0; c < 256; ++c)
      wa = __fmaf_rn(H[(c << 6) + (t ^ ((c >> 2) & 31))], Wd2[c], wa);
    const float w = __fadd_rn(wa, bd2[0]);
    wkey[m0 + t] = __fdiv_rn(w, 0.1f);
  }
}

// ---------------- per-batch top-K: u64-packed bitonic (key desc, tie: lower idx) ----------------
__global__ void __launch_bounds__(1024) void_guard();
__global__ void __launch_bounds__(1024) topk_kernel(
    const float* __restrict__ wv, const float* __restrict__ xyzs,
    int* __restrict__ idx_out, float* __restrict__ out_xyz,
    float* __restrict__ out_idx) {
  __shared__ unsigned long long vals[2048];
  const int b = blockIdx.x, t = threadIdx.x;
#pragma unroll
  for (int h = 0; h < 2; ++h) {
    const int i = (h << 10) + t;
    const unsigned int u = __float_as_uint(wv[(b << 11) + i]);
    const unsigned int up = ((int)u < 0) ? ~u : (u | 0x80000000u);
    vals[i] = (((unsigned long long)(~up)) << 32) | (unsigned int)i;
  }
  __syncthreads();
  for (int k = 2; k <= 2048; k <<= 1) {
    for (int j = k >> 1; j > 0; j >>= 1) {
      for (int half = 0; half < 2; ++half) {
        const int i = (half << 10) | t;
        const int ixj = i ^ j;
        if (ixj > i) {
          const unsigned long long vi = vals[i], vj = vals[ixj];
          const bool up = ((i & k) == 0);
          if ((vi > vj) == up) { vals[i] = vj; vals[ixj] = vi; }
        }
      }
      __syncthreads();
    }
  }
  const int sel = (int)(vals[t] & 0xffffffffu);
  idx_out[(b << 10) + t] = sel;
  out_idx[(b << 10) + t] = (float)sel;
  const long o = ((long)((b << 10) + t)) * 3;
  const long s3 = ((long)((b << 11) + sel)) * 3;
  out_xyz[o] = xyzs[s3]; out_xyz[o + 1] = xyzs[s3 + 1]; out_xyz[o + 2] = xyzs[s3 + 2];
}

// ---------------- weight prep (merged): W (256x256 f32) -> P bf16 slabs [kc][n][32] ----------------
__global__ __launch_bounds__(256) void prep_w2(const float* __restrict__ W1,
    const float* __restrict__ W2, unsigned short* __restrict__ P1,
    unsigned short* __restrict__ P2) {
  const int g = blockIdx.x;
  const float* W = (g < 8) ? W1 : W2;
  unsigned short* P = (g < 8) ? P1 : P2;
  const int kc = g & 7, n = threadIdx.x;
  unsigned int packed[16];
#pragma unroll
  for (int i = 0; i < 16; ++i) {
    const float a = W[(((kc << 5) + 2 * i) << 8) + n];
    const float bq = W[(((kc << 5) + 2 * i + 1) << 8) + n];
    packed[i] = bf16rne(a) | (bf16rne(bq) << 16);
  }
  uint4* dst = (uint4*)(P + (((kc << 8) + n) << 5));
#pragma unroll
  for (int q = 0; q < 4; ++q)
    dst[q] = make_uint4(packed[4 * q], packed[4 * q + 1], packed[4 * q + 2], packed[4 * q + 3]);
}

// ---------------- fused up-branch: gather -> bf16 MFMA GEMM1(relu) -> GEMM2 -> transposed out ----------------
#define APITCH 264
#define BPITCH 40
__global__ void __launch_bounds__(256) up_mfma(
    const float* __restrict__ fbuf, const int* __restrict__ idxm,
    const unsigned short* __restrict__ Wu1P, const float* __restrict__ bu1,
    const unsigned short* __restrict__ Wu2P, const float* __restrict__ bu2,
    float* __restrict__ out_feat) {
  __shared__ __align__(16) char smem[64 * APITCH * 2 + 256 * BPITCH * 2 + 2048];
  unsigned short* As = (unsigned short*)smem;                       // 33792 B (later Hs)
  unsigned short* Bs = (unsigned short*)(smem + 64 * APITCH * 2);   // 20480 B (later T)
  float* bias1 = (float*)(smem + 64 * APITCH * 2 + 256 * BPITCH * 2);
  float* bias2 = bias1 + 256;
  float* T = (float*)(smem + 64 * APITCH * 2);                      // 64x66 f32 = 16896 B

  const int t = threadIdx.x;
  const int m0 = blockIdx.x << 6;
  const int quad = (t >> 4) & 3, ln = t & 15, w = t >> 6;

  bias1[t] = bu1[t];
  bias2[t] = bu2[t];

  // gather + cvt: As[r][c] bf16, r = t&63, cols (t>>6)*64..+63
  {
    const int r = t & 63, cseg = t >> 6;
    const int m = m0 + r;
    const long srow = (long)(((m >> 10) << 11) + idxm[m]) << 8;
    const float* src = fbuf + srow + (cseg << 6);
    unsigned short* dst = As + r * APITCH + (cseg << 6);
#pragma unroll
    for (int u = 0; u < 16; ++u) {
      const float4 v = *(const float4*)(src + (u << 2));
      const unsigned int lo = bf16rne(v.x) | (bf16rne(v.y) << 16);
      const unsigned int hi = bf16rne(v.z) | (bf16rne(v.w) << 16);
      *(uint2*)(dst + (u << 2)) = make_uint2(lo, hi);
    }
  }

  f32x4 acc[16];
#pragma unroll
  for (int i = 0; i < 16; ++i) acc[i] = (f32x4){0.f, 0.f, 0.f, 0.f};

  // ---- GEMM1: hu = gathered_f @ Wu1 ----
  for (int kc = 0; kc < 8; ++kc) {
    __syncthreads();
    const uint4* sb = (const uint4*)(Wu1P + (((kc << 8) + t) << 5));
    uint4* db = (uint4*)(Bs + t * BPITCH);
    db[0] = sb[0]; db[1] = sb[1]; db[2] = sb[2]; db[3] = sb[3];
    __syncthreads();
    const short8 a = *(const short8*)(As + ((w << 4) + ln) * APITCH + (kc << 5) + (quad << 3));
#pragma unroll
    for (int nt = 0; nt < 16; ++nt) {
      const short8 b = *(const short8*)(Bs + ((nt << 4) + ln) * BPITCH + (quad << 3));
      acc[nt] = __builtin_amdgcn_mfma_f32_16x16x32_bf16(a, b, acc[nt], 0, 0, 0);
    }
  }

  // ---- relu + bias -> Hs (alias As) ----
  __syncthreads();
  unsigned short* Hs = As;
#pragma unroll
  for (int nt = 0; nt < 16; ++nt) {
    const int c = (nt << 4) + ln;
    const float bb = bias1[c];
#pragma unroll
    for (int rr = 0; rr < 4; ++rr) {
      const float h = fmaxf(acc[nt][rr] + bb, 0.0f);
      Hs[((w << 4) + (quad << 2) + rr) * APITCH + c] = (unsigned short)bf16rne(h);
    }
  }
#pragma unroll
  for (int i = 0; i < 16; ++i) acc[i] = (f32x4){0.f, 0.f, 0.f, 0.f};

  // ---- GEMM2: nf = hu @ Wu2 ----
  for (int kc = 0; kc < 8; ++kc) {
    __syncthreads();
    const uint4* sb = (const uint4*)(Wu2P + (((kc << 8) + t) << 5));
    uint4* db = (uint4*)(Bs + t * BPITCH);
    db[0] = sb[0]; db[1] = sb[1]; db[2] = sb[2]; db[3] = sb[3];
    __syncthreads();
    const short8 a = *(const short8*)(Hs + ((w << 4) + ln) * APITCH + (kc << 5) + (quad << 3));
#pragma unroll
    for (int nt = 0; nt < 16; ++nt) {
      const short8 b = *(const short8*)(Bs + ((nt << 4) + ln) * BPITCH + (quad << 3));
      acc[nt] = __builtin_amdgcn_mfma_f32_16x16x32_bf16(a, b, acc[nt], 0, 0, 0);
    }
  }

  // ---- epilogue: +bu2, transpose via LDS, write out_feat (B,C,K) coalesced ----
  const int bb = m0 >> 10, kbase = m0 & 1023;
  for (int ci = 0; ci < 4; ++ci) {
    __syncthreads();
#pragma unroll
    for (int q = 0; q < 4; ++q) {
      const int nt = (ci << 2) + q;
      const int cloc = (q << 4) + ln;
      const float b2 = bias2[(nt << 4) + ln];
#pragma unroll
      for (int rr = 0; rr < 4; ++rr)
        T[cloc * 66 + ((w << 4) + (quad << 2) + rr)] = acc[nt][rr] + b2;
    }
    __syncthreads();
#pragma unroll
    for (int p = 0; p < 16; ++p) {
      const int cl = (p << 2) + (t >> 6);
      const int m = t & 63;
      out_feat[((long)((bb << 8) + (ci << 6) + cl) << 10) + kbase + m] = T[cl * 66 + m];
    }
  }
}

extern "C" void kernel_launch(void* const* d_in, const int* in_sizes, int n_in,
                              void* d_out, int out_size, void* d_ws, size_t ws_size,
                              hipStream_t stream) {
  const float* xyzs     = (const float*)d_in[0];
  const float* features = (const float*)d_in[1];
  const float* ln_gamma = (const float*)d_in[2];
  const float* ln_beta  = (const float*)d_in[3];
  const float* Wu1      = (const float*)d_in[4];
  const float* bu1      = (const float*)d_in[5];
  const float* Wu2      = (const float*)d_in[6];
  const float* bu2      = (const float*)d_in[7];
  const float* Wd1      = (const float*)d_in[8];
  const float* bd1      = (const float*)d_in[9];
  const float* Wd2      = (const float*)d_in[10];
  const float* bd2      = (const float*)d_in[11];

  char* ws = (char*)d_ws;
  float* fbuf = (float*)ws;                              // 16 MB
  unsigned short* Wu1P = (unsigned short*)(ws + 33554432);  // 128 KB bf16 slabs
  unsigned short* Wu2P = (unsigned short*)(ws + 33685504);  // 128 KB
  float* wv   = (float*)(ws + 50331648);                 // 16384 f32
  int*   idx  = (int*)(ws + 50397184);                   // 8192 i32

  float* out_xyz  = (float*)d_out;            // (8,1024,3)
  float* out_feat = out_xyz + 24576;          // (8,256,1024)
  float* out_idx  = out_feat + 2097152;       // (8,1024)

  prep_w2<<<16, 256, 0, stream>>>(Wu1, Wu2, Wu1P, Wu2P);
  ln_lds<<<256, 64, 0, stream>>>(features, ln_gamma, ln_beta, fbuf);
  wgemm_w<<<256, 512, 0, stream>>>(fbuf, Wd1, bd1, Wd2, bd2, wv);
  topk_kernel<<<8, 1024, 0, stream>>>(wv, xyzs, idx, out_xyz, out_idx);
  up_mfma<<<128, 256, 0, stream>>>(fbuf, idx, Wu1P, bu1, Wu2P, bu2, out_feat);
}

// Round 2
// 233.694 us; speedup vs baseline: 1.0166x; 1.0166x over previous
//
#include <hip/hip_runtime.h>

#define B_DIM 8
#define N_DIM 2048
#define C_DIM 256
#define K_SEL 1024

typedef __attribute__((ext_vector_type(8))) short short8;
typedef __attribute__((ext_vector_type(4))) float f32x4;

__device__ __forceinline__ unsigned int bf16rne(float x) {
  unsigned int u = __float_as_uint(x);
  return (u + 0x7fffu + ((u >> 16) & 1u)) >> 16;
}

// ---------------- LayerNorm, numpy-bit-exact, LDS-staged (unchanged, verified) ----------------
__global__ __launch_bounds__(64) void ln_lds(const float* __restrict__ feat,
    const float* __restrict__ gamma, const float* __restrict__ beta,
    float* __restrict__ fbuf) {
  __shared__ float tile[256 * 64];   // 64 KB exactly
  const int t = threadIdx.x;
  const int m0 = blockIdx.x << 6;
  const int b = m0 >> 11, n0 = m0 & 2047;

  const int cg = t >> 4, nl4 = (t & 15) << 2;
  for (int pass = 0; pass < 64; ++pass) {
    const int c = (pass << 2) + cg;
    const float4 v = *(const float4*)(feat + (((long)((b << 8) + c)) << 11) + n0 + nl4);
    const int sw = c & 31;
    float* row = tile + (c << 6);
    row[(nl4 + 0) ^ sw] = v.x; row[(nl4 + 1) ^ sw] = v.y;
    row[(nl4 + 2) ^ sw] = v.z; row[(nl4 + 3) ^ sw] = v.w;
  }
  __syncthreads();

  // mean: sequential ascending single chain (numpy strided-axis outer reduction)
  float acc = tile[t];
  for (int c = 1; c < 256; ++c) acc = __fadd_rn(acc, tile[(c << 6) + (t ^ (c & 31))]);
  const float mu = __fdiv_rn(acc, 256.0f);

  // var: numpy pairwise (2 halves x 8 accumulators) on contiguous (x-mu)^2
  float pw[2];
#pragma unroll
  for (int blk = 0; blk < 2; ++blk) {
    const int c0 = blk << 7;
    float r8[8];
#pragma unroll
    for (int j = 0; j < 8; ++j) {
      float d = __fsub_rn(tile[((c0 + j) << 6) + (t ^ ((c0 + j) & 31))], mu);
      r8[j] = __fmul_rn(d, d);
    }
    for (int i = 8; i < 128; i += 8) {
#pragma unroll
      for (int j = 0; j < 8; ++j) {
        const int c = c0 + i + j;
        float d = __fsub_rn(tile[(c << 6) + (t ^ (c & 31))], mu);
        r8[j] = __fadd_rn(r8[j], __fmul_rn(d, d));
      }
    }
    pw[blk] = __fadd_rn(__fadd_rn(__fadd_rn(r8[0], r8[1]), __fadd_rn(r8[2], r8[3])),
                        __fadd_rn(__fadd_rn(r8[4], r8[5]), __fadd_rn(r8[6], r8[7])));
  }
  const float var = __fdiv_rn(__fadd_rn(pw[0], pw[1]), 256.0f);
  const float rs = __fdiv_rn(1.0f, __fsqrt_rn(__fadd_rn(var, 1e-6f)));

  float ga[4], be[4];
#pragma unroll
  for (int q = 0; q < 4; ++q) { ga[q] = gamma[(q << 6) + t]; be[q] = beta[(q << 6) + t]; }
  for (int r = 0; r < 64; ++r) {
    const float mu_r = __shfl(mu, r, 64);
    const float rs_r = __shfl(rs, r, 64);
    float* orow = fbuf + (((long)(m0 + r)) << 8);
#pragma unroll
    for (int q = 0; q < 4; ++q) {
      const int c = (q << 6) + t;
      const float x = tile[(c << 6) + (r ^ (c & 31))];
      orow[c] = __fadd_rn(__fmul_rn(__fmul_rn(__fsub_rn(x, mu_r), rs_r), ga[q]), be[q]);
    }
  }
}

// ---------------- fused down-GEMM + w-chain, 512 threads (bit-exact chains) ----------------
// v3: A is wave-uniform (rowT = t>>6) -> broadcast global loads (L1-line resident),
// 2-group-deep STATIC pipeline (4 rotating float4[8] buffers, indices static after unroll).
// LDS per kk per wave: 1 spanning B ds_read_b128 only -> per-CU LDS 96 cyc < VALU 128 cyc.
// __launch_bounds__(512,2) caps at 2 waves/SIMD => 256-VGPR budget, NO SPILL (v2 failed
// because the default heuristic capped VGPRs at 128 and spilled the pipeline arrays:
// WRITE_SIZE 64KB -> 24MB scratch). B-staging lanes remapped to consecutive float4s
// (conflict-free writes). FMA chain per (m,c) stays ascending-k single chain -> bit-exact.
__global__ void __launch_bounds__(512, 2) wgemm_w(
    const float* __restrict__ A, const float* __restrict__ Wd1,
    const float* __restrict__ bd1, const float* __restrict__ Wd2,
    const float* __restrict__ bd2, float* __restrict__ wkey) {
  __shared__ __align__(16) char smem[65536];
  float* Bs0f = (float*)smem;                  // 16x260 f32 = 16640 B
  float* Bs1f = (float*)(smem + 16640);        // 16640 B (double buffer)
  float* H = (float*)smem;                     // 256x64 f32 = 64 KB (epilogue alias)

  const int t = threadIdx.x;
  const int m0 = blockIdx.x << 6;
  const int rowT = t >> 6, colT = t & 63;      // rowT uniform per wave
  const int bk = t >> 5, bl4 = (t & 31) << 2;  // staging: lane-consecutive float4s
  const int wrow = __builtin_amdgcn_readfirstlane(m0 + (rowT << 3));
  const float* aw = A + ((long)wrow << 8);     // wave's 8 rows; row i at +i*256

  float acc[8][4] = {};

  // B prologue: stage chunk 0 into Bs0 (conflict-free: lanes write consecutive float4s)
  {
    const float* brow = Wd1 + (bk << 8);
    *(float4*)(Bs0f + bk * 260 + bl4)       = *(const float4*)(brow + bl4);
    *(float4*)(Bs0f + bk * 260 + bl4 + 128) = *(const float4*)(brow + bl4 + 128);
  }

  // A pipeline prologue: groups 0,1 (k=0..3, 4..7) into buffers 0,1
  float4 ab[4][8];
#pragma unroll
  for (int i = 0; i < 8; ++i) ab[0][i] = *(const float4*)(aw + (i << 8) + 0);
#pragma unroll
  for (int i = 0; i < 8; ++i) ab[1][i] = *(const float4*)(aw + (i << 8) + 4);

  __syncthreads();

  const float* Bc = Bs0f;
  float* Bn = Bs1f;
  for (int c16 = 0; c16 < 16; ++c16) {
    // issue next B-chunk global loads (wraps on last iter; then unused)
    float4 r0, r1;
    {
      const int knext = (c16 + 1) & 15;
      const float* brow = Wd1 + (((knext << 4) + bk) << 8);
      r0 = *(const float4*)(brow + bl4);
      r1 = *(const float4*)(brow + bl4 + 128);
    }
#pragma unroll
    for (int g = 0; g < 4; ++g) {               // group G = c16*4+g covers k=4G..4G+3
      // prefetch A for group G+2 into buffer (g+2)&3 (2 groups ~512 cyc ahead)
      const int kpre = (((c16 << 2) + g + 2) << 2) & 255;
#pragma unroll
      for (int i = 0; i < 8; ++i)
        ab[(g + 2) & 3][i] = *(const float4*)(aw + (i << 8) + kpre);
#pragma unroll
      for (int kk = 0; kk < 4; ++kk) {          // k ascending: single FMA chain per (m,c)
        const float4 b = *(const float4*)(Bc + ((g << 2) + kk) * 260 + (colT << 2));
        const float bbv[4] = {b.x, b.y, b.z, b.w};
#pragma unroll
        for (int i = 0; i < 8; ++i) {
          const float av = (kk == 0) ? ab[g & 3][i].x : (kk == 1) ? ab[g & 3][i].y
                         : (kk == 2) ? ab[g & 3][i].z : ab[g & 3][i].w;
#pragma unroll
          for (int j = 0; j < 4; ++j)
            acc[i][j] = __fmaf_rn(av, bbv[j], acc[i][j]);
        }
      }
    }
    if (c16 < 15) {
      // write next chunk into Bn; safe: all waves finished reading Bn before the
      // barrier that ended the previous chunk
      *(float4*)(Bn + bk * 260 + bl4)       = r0;
      *(float4*)(Bn + bk * 260 + bl4 + 128) = r1;
      const float* tmp = Bc; Bc = Bn; Bn = (float*)tmp;
    }
    __syncthreads();   // one barrier per chunk; final one guards the H alias below
  }

  // epilogue: bias + relu -> H[c][m] swizzled (unchanged, verified)
  const float4 bd = *(const float4*)(bd1 + (colT << 2));
  const float ba[4] = {bd.x, bd.y, bd.z, bd.w};
#pragma unroll
  for (int i = 0; i < 8; ++i) {
    const int m = (rowT << 3) + i;
#pragma unroll
    for (int j = 0; j < 4; ++j) {
      const int c = (colT << 2) + j;
      H[(c << 6) + (m ^ ((c >> 2) & 31))] = fmaxf(__fadd_rn(acc[i][j], ba[j]), 0.0f);
    }
  }
  __syncthreads();

  // w-chain: ascending-c single FMA chain; key = (w+bd2)/0.1f (unchanged, verified)
  if (t < 64) {
    float wa = 0.0f;
    for (int c = 0; c < 256; ++c)
      wa = __fmaf_rn(H[(c << 6) + (t ^ ((c >> 2) & 31))], Wd2[c], wa);
    const float w = __fadd_rn(wa, bd2[0]);
    wkey[m0 + t] = __fdiv_rn(w, 0.1f);
  }
}

// ---------------- per-batch top-K: u64-packed bitonic (key desc, tie: lower idx) ----------------
__global__ void __launch_bounds__(1024) topk_kernel(
    const float* __restrict__ wv, const float* __restrict__ xyzs,
    int* __restrict__ idx_out, float* __restrict__ out_xyz,
    float* __restrict__ out_idx) {
  __shared__ unsigned long long vals[2048];
  const int b = blockIdx.x, t = threadIdx.x;
#pragma unroll
  for (int h = 0; h < 2; ++h) {
    const int i = (h << 10) + t;
    const unsigned int u = __float_as_uint(wv[(b << 11) + i]);
    const unsigned int up = ((int)u < 0) ? ~u : (u | 0x80000000u);
    vals[i] = (((unsigned long long)(~up)) << 32) | (unsigned int)i;
  }
  __syncthreads();
  for (int k = 2; k <= 2048; k <<= 1) {
    for (int j = k >> 1; j > 0; j >>= 1) {
      for (int half = 0; half < 2; ++half) {
        const int i = (half << 10) | t;
        const int ixj = i ^ j;
        if (ixj > i) {
          const unsigned long long vi = vals[i], vj = vals[ixj];
          const bool up = ((i & k) == 0);
          if ((vi > vj) == up) { vals[i] = vj; vals[ixj] = vi; }
        }
      }
      __syncthreads();
    }
  }
  const int sel = (int)(vals[t] & 0xffffffffu);
  idx_out[(b << 10) + t] = sel;
  out_idx[(b << 10) + t] = (float)sel;
  const long o = ((long)((b << 10) + t)) * 3;
  const long s3 = ((long)((b << 11) + sel)) * 3;
  out_xyz[o] = xyzs[s3]; out_xyz[o + 1] = xyzs[s3 + 1]; out_xyz[o + 2] = xyzs[s3 + 2];
}

// ---------------- weight prep (merged): W (256x256 f32) -> P bf16 slabs [kc][n][32] ----------------
__global__ __launch_bounds__(256) void prep_w2(const float* __restrict__ W1,
    const float* __restrict__ W2, unsigned short* __restrict__ P1,
    unsigned short* __restrict__ P2) {
  const int g = blockIdx.x;
  const float* W = (g < 8) ? W1 : W2;
  unsigned short* P = (g < 8) ? P1 : P2;
  const int kc = g & 7, n = threadIdx.x;
  unsigned int packed[16];
#pragma unroll
  for (int i = 0; i < 16; ++i) {
    const float a = W[(((kc << 5) + 2 * i) << 8) + n];
    const float bq = W[(((kc << 5) + 2 * i + 1) << 8) + n];
    packed[i] = bf16rne(a) | (bf16rne(bq) << 16);
  }
  uint4* dst = (uint4*)(P + (((kc << 8) + n) << 5));
#pragma unroll
  for (int q = 0; q < 4; ++q)
    dst[q] = make_uint4(packed[4 * q], packed[4 * q + 1], packed[4 * q + 2], packed[4 * q + 3]);
}

// ---------------- fused up-branch: gather -> bf16 MFMA GEMM1(relu) -> GEMM2 -> transposed out ----------------
#define APITCH 264
#define BPITCH 40
__global__ void __launch_bounds__(256) up_mfma(
    const float* __restrict__ fbuf, const int* __restrict__ idxm,
    const unsigned short* __restrict__ Wu1P, const float* __restrict__ bu1,
    const unsigned short* __restrict__ Wu2P, const float* __restrict__ bu2,
    float* __restrict__ out_feat) {
  __shared__ __align__(16) char smem[64 * APITCH * 2 + 256 * BPITCH * 2 + 2048];
  unsigned short* As = (unsigned short*)smem;                       // 33792 B (later Hs)
  unsigned short* Bs = (unsigned short*)(smem + 64 * APITCH * 2);   // 20480 B (later T)
  float* bias1 = (float*)(smem + 64 * APITCH * 2 + 256 * BPITCH * 2);
  float* bias2 = bias1 + 256;
  float* T = (float*)(smem + 64 * APITCH * 2);                      // 64x66 f32 = 16896 B

  const int t = threadIdx.x;
  const int m0 = blockIdx.x << 6;
  const int quad = (t >> 4) & 3, ln = t & 15, w = t >> 6;

  bias1[t] = bu1[t];
  bias2[t] = bu2[t];

  // gather + cvt: As[r][c] bf16, r = t&63, cols (t>>6)*64..+63
  {
    const int r = t & 63, cseg = t >> 6;
    const int m = m0 + r;
    const long srow = (long)(((m >> 10) << 11) + idxm[m]) << 8;
    const float* src = fbuf + srow + (cseg << 6);
    unsigned short* dst = As + r * APITCH + (cseg << 6);
#pragma unroll
    for (int u = 0; u < 16; ++u) {
      const float4 v = *(const float4*)(src + (u << 2));
      const unsigned int lo = bf16rne(v.x) | (bf16rne(v.y) << 16);
      const unsigned int hi = bf16rne(v.z) | (bf16rne(v.w) << 16);
      *(uint2*)(dst + (u << 2)) = make_uint2(lo, hi);
    }
  }

  f32x4 acc[16];
#pragma unroll
  for (int i = 0; i < 16; ++i) acc[i] = (f32x4){0.f, 0.f, 0.f, 0.f};

  // ---- GEMM1: hu = gathered_f @ Wu1 ----
  for (int kc = 0; kc < 8; ++kc) {
    __syncthreads();
    const uint4* sb = (const uint4*)(Wu1P + (((kc << 8) + t) << 5));
    uint4* db = (uint4*)(Bs + t * BPITCH);
    db[0] = sb[0]; db[1] = sb[1]; db[2] = sb[2]; db[3] = sb[3];
    __syncthreads();
    const short8 a = *(const short8*)(As + ((w << 4) + ln) * APITCH + (kc << 5) + (quad << 3));
#pragma unroll
    for (int nt = 0; nt < 16; ++nt) {
      const short8 b = *(const short8*)(Bs + ((nt << 4) + ln) * BPITCH + (quad << 3));
      acc[nt] = __builtin_amdgcn_mfma_f32_16x16x32_bf16(a, b, acc[nt], 0, 0, 0);
    }
  }

  // ---- relu + bias -> Hs (alias As) ----
  __syncthreads();
  unsigned short* Hs = As;
#pragma unroll
  for (int nt = 0; nt < 16; ++nt) {
    const int c = (nt << 4) + ln;
    const float bb = bias1[c];
#pragma unroll
    for (int rr = 0; rr < 4; ++rr) {
      const float h = fmaxf(acc[nt][rr] + bb, 0.0f);
      Hs[((w << 4) + (quad << 2) + rr) * APITCH + c] = (unsigned short)bf16rne(h);
    }
  }
#pragma unroll
  for (int i = 0; i < 16; ++i) acc[i] = (f32x4){0.f, 0.f, 0.f, 0.f};

  // ---- GEMM2: nf = hu @ Wu2 ----
  for (int kc = 0; kc < 8; ++kc) {
    __syncthreads();
    const uint4* sb = (const uint4*)(Wu2P + (((kc << 8) + t) << 5));
    uint4* db = (uint4*)(Bs + t * BPITCH);
    db[0] = sb[0]; db[1] = sb[1]; db[2] = sb[2]; db[3] = sb[3];
    __syncthreads();
    const short8 a = *(const short8*)(Hs + ((w << 4) + ln) * APITCH + (kc << 5) + (quad << 3));
#pragma unroll
    for (int nt = 0; nt < 16; ++nt) {
      const short8 b = *(const short8*)(Bs + ((nt << 4) + ln) * BPITCH + (quad << 3));
      acc[nt] = __builtin_amdgcn_mfma_f32_16x16x32_bf16(a, b, acc[nt], 0, 0, 0);
    }
  }

  // ---- epilogue: +bu2, transpose via LDS, write out_feat (B,C,K) coalesced ----
  const int bb = m0 >> 10, kbase = m0 & 1023;
  for (int ci = 0; ci < 4; ++ci) {
    __syncthreads();
#pragma unroll
    for (int q = 0; q < 4; ++q) {
      const int nt = (ci << 2) + q;
      const int cloc = (q << 4) + ln;
      const float b2 = bias2[(nt << 4) + ln];
#pragma unroll
      for (int rr = 0; rr < 4; ++rr)
        T[cloc * 66 + ((w << 4) + (quad << 2) + rr)] = acc[nt][rr] + b2;
    }
    __syncthreads();
#pragma unroll
    for (int p = 0; p < 16; ++p) {
      const int cl = (p << 2) + (t >> 6);
      const int m = t & 63;
      out_feat[((long)((bb << 8) + (ci << 6) + cl) << 10) + kbase + m] = T[cl * 66 + m];
    }
  }
}

extern "C" void kernel_launch(void* const* d_in, const int* in_sizes, int n_in,
                              void* d_out, int out_size, void* d_ws, size_t ws_size,
                              hipStream_t stream) {
  const float* xyzs     = (const float*)d_in[0];
  const float* features = (const float*)d_in[1];
  const float* ln_gamma = (const float*)d_in[2];
  const float* ln_beta  = (const float*)d_in[3];
  const float* Wu1      = (const float*)d_in[4];
  const float* bu1      = (const float*)d_in[5];
  const float* Wu2      = (const float*)d_in[6];
  const float* bu2      = (const float*)d_in[7];
  const float* Wd1      = (const float*)d_in[8];
  const float* bd1      = (const float*)d_in[9];
  const float* Wd2      = (const float*)d_in[10];
  const float* bd2      = (const float*)d_in[11];

  char* ws = (char*)d_ws;
  float* fbuf = (float*)ws;                              // 16 MB
  unsigned short* Wu1P = (unsigned short*)(ws + 33554432);  // 128 KB bf16 slabs
  unsigned short* Wu2P = (unsigned short*)(ws + 33685504);  // 128 KB
  float* wv   = (float*)(ws + 50331648);                 // 16384 f32
  int*   idx  = (int*)(ws + 50397184);                   // 8192 i32

  float* out_xyz  = (float*)d_out;            // (8,1024,3)
  float* out_feat = out_xyz + 24576;          // (8,256,1024)
  float* out_idx  = out_feat + 2097152;       // (8,1024)

  prep_w2<<<16, 256, 0, stream>>>(Wu1, Wu2, Wu1P, Wu2P);
  ln_lds<<<256, 64, 0, stream>>>(features, ln_gamma, ln_beta, fbuf);
  wgemm_w<<<256, 512, 0, stream>>>(fbuf, Wd1, bd1, Wd2, bd2, wv);
  topk_kernel<<<8, 1024, 0, stream>>>(wv, xyzs, idx, out_xyz, out_idx);
  up_mfma<<<128, 256, 0, stream>>>(fbuf, idx, Wu1P, bu1, Wu2P, bu2, out_feat);
}